// Round 14
// baseline (186.693 us; speedup 1.0000x reference)
//
#include <hip/hip_runtime.h>
#include <hip/hip_bf16.h>
#include <math.h>

// Problem constants
constexpr int Bb   = 2;
constexpr int S    = 2048;
constexpr int D    = 1024;
constexpr int H    = 16;
constexpr int Dh   = 64;
constexpr int HALF = 32;            // Dh/2
constexpr int M    = Bb * S;        // 4096 rows in the projection GEMMs
constexpr int K    = 1024;
constexpr int N    = 1024;

typedef __attribute__((ext_vector_type(8))) short short8;   // 8 bf16 (4 VGPRs)
typedef __attribute__((ext_vector_type(4))) float f32x4;    // MFMA C/D

// float -> bf16 bits, round-to-nearest-even
__device__ __forceinline__ unsigned short f2bf(float f) {
    unsigned int u = __float_as_uint(f);
    unsigned int r = (u + 0x7fffu + ((u >> 16) & 1u)) >> 16;
    return (unsigned short)r;
}

// async global->LDS, 16B per lane; LDS dest = wave-uniform base + lane*16
__device__ __forceinline__ void gl_lds16(const unsigned short* g, unsigned short* lds_base) {
    __builtin_amdgcn_global_load_lds(
        (const __attribute__((address_space(1))) unsigned int*)g,
        (__attribute__((address_space(3))) unsigned int*)lds_base, 16, 0, 0);
}

// ---------------------------------------------------------------------------
// Fused prep: blocks [0,256) rope tables (double precision),
// [256,4352) x fp32->bf16, [4352,5376) W fp32 [k][n] -> bf16 W^T [n][k].
// ---------------------------------------------------------------------------
__global__ __launch_bounds__(256) void prep_kernel(
    const float* __restrict__ x,
    const float* W0, const float* W1, const float* W2, const float* W3,
    unsigned short* __restrict__ xb,
    unsigned short* T0, unsigned short* T1, unsigned short* T2, unsigned short* T3,
    float* __restrict__ cosT, float* __restrict__ sinT)
{
    __shared__ float tile[64][65];
    const int bid = blockIdx.x;
    const int tid = threadIdx.x;

    if (bid < 256) {
        int idx = bid * 256 + tid;            // S*HALF = 65536
        int s = idx >> 5;
        int i = idx & 31;
        double freq = exp(-(double)i * (log(10000.0) / 32.0));
        double ang  = (double)s * freq;
        cosT[idx] = (float)cos(ang);
        sinT[idx] = (float)sin(ang);
    } else if (bid < 256 + 4096) {
        size_t i = (size_t)(bid - 256) * 256 + tid;   // over M*K/4
        float4 v = *(const float4*)(x + i * 4);
        ushort4 pk;
        pk.x = f2bf(v.x); pk.y = f2bf(v.y); pk.z = f2bf(v.z); pk.w = f2bf(v.w);
        *(ushort4*)(xb + i * 4) = pk;
    } else {
        int wb = bid - 4352;
        int z  = wb >> 8;
        int rem = wb & 255;
        const float* W = (z == 0) ? W0 : (z == 1) ? W1 : (z == 2) ? W2 : W3;
        unsigned short* T = (z == 0) ? T0 : (z == 1) ? T1 : (z == 2) ? T2 : T3;
        const int bk = (rem >> 4) * 64;   // src row block (k)
        const int bn = (rem & 15) * 64;   // src col block (n)
        const int lr = tid >> 4;          // 0..15
        const int lc = (tid & 15) * 4;    // float4 col

        #pragma unroll
        for (int i = 0; i < 4; ++i) {
            int r = lr + i * 16;
            float4 v = *(const float4*)(W + (size_t)(bk + r) * N + bn + lc);
            tile[r][lc + 0] = v.x; tile[r][lc + 1] = v.y;
            tile[r][lc + 2] = v.z; tile[r][lc + 3] = v.w;
        }
        __syncthreads();
        #pragma unroll
        for (int i = 0; i < 4; ++i) {
            int nr = lr + i * 16;
            ushort4 pk;
            pk.x = f2bf(tile[lc + 0][nr]);
            pk.y = f2bf(tile[lc + 1][nr]);
            pk.z = f2bf(tile[lc + 2][nr]);
            pk.w = f2bf(tile[lc + 3][nr]);
            *(ushort4*)(T + (size_t)(bn + nr) * K + bk + lc) = pk;
        }
    }
}

// ---------------------------------------------------------------------------
// QKV bf16 MFMA GEMM v6b (unchanged): BM=256 x BN=192, BK=64, 4-phase
// counted pipeline, grid (16,16) = 256 blocks = 1/CU. rot=r swizzle
// (bank conflicts 2.88M -> 0 verified r13).
// ---------------------------------------------------------------------------
__global__ __launch_bounds__(512, 2) void gemm_qkv_kernel(
    const unsigned short* __restrict__ A,
    const unsigned short* __restrict__ BT,
    unsigned short* outQ, unsigned short* outK, unsigned short* outV,
    const float* __restrict__ cosT, const float* __restrict__ sinT)
{
    constexpr int NT    = 16;           // K / 64 k-tiles
    constexpr int ASLOT = 256 * 64;     // shorts per A slot (32 KB)
    constexpr int BSLOT = 192 * 64;     // shorts per B slot (24 KB)
    __shared__ __align__(16) unsigned short As[2 * ASLOT];   // 64 KB
    __shared__ __align__(16) unsigned short Bs[2 * BSLOT];   // 48 KB

    const int tid  = threadIdx.x;
    const int wid  = tid >> 6;
    const int lane = tid & 63;
    const int col  = lane & 15;
    const int quad = lane >> 4;
    const int wr   = wid >> 2;        // m-half owner (0..1), 128 rows
    const int wc   = wid & 3;         // n-quarter owner (0..3), 48 cols

    const int mbase = blockIdx.y * 256;
    const int nbase = blockIdx.x * 192;

    const int srow8 = lane >> 3;      // 0..7
    const int sch8  = lane & 7;       // 16B chunk
    const unsigned short *pA[4], *pB[3];
    unsigned short *dA[4], *dB[3];
    #pragma unroll
    for (int w = 0; w < 4; ++w) {
        int r = wid * 32 + w * 8 + srow8;
        pA[w] = A + (size_t)(mbase + r) * K + ((sch8 + r) & 7) * 8;   // rot=r
        dA[w] = &As[(wid * 32 + w * 8) * 64];
    }
    #pragma unroll
    for (int w = 0; w < 3; ++w) {
        int r = wid * 24 + w * 8 + srow8;
        pB[w] = BT + (size_t)(nbase + r) * K + ((sch8 + r) & 7) * 8;  // rot=r
        dB[w] = &Bs[(wid * 24 + w * 8) * 64];
    }

    int aoff[2][8], boff[2][3];
    #pragma unroll
    for (int kh = 0; kh < 2; ++kh) {
        #pragma unroll
        for (int f = 0; f < 8; ++f) {
            int r = wr * 128 + f * 16 + col;
            aoff[kh][f] = r * 64 + (((kh * 4 + quad) - r) & 7) * 8;   // rot=r
        }
        #pragma unroll
        for (int n = 0; n < 3; ++n) {
            int r = wc * 48 + n * 16 + col;
            boff[kh][n] = r * 64 + (((kh * 4 + quad) - r) & 7) * 8;   // rot=r
        }
    }

    f32x4 acc[8][3];
    #pragma unroll
    for (int f = 0; f < 8; ++f)
        #pragma unroll
        for (int n = 0; n < 3; ++n) acc[f][n] = (f32x4)0.f;

    auto stageA = [&](int slot) {       // 4 instrs
        #pragma unroll
        for (int w = 0; w < 4; ++w) { gl_lds16(pA[w], dA[w] + slot * ASLOT); pA[w] += 64; }
    };
    auto stageB = [&](int slot) {       // 3 instrs
        #pragma unroll
        for (int w = 0; w < 3; ++w) { gl_lds16(pB[w], dB[w] + slot * BSLOT); pB[w] += 64; }
    };

    stageA(0); stageB(0);
    asm volatile("s_waitcnt vmcnt(0)" ::: "memory");
    __builtin_amdgcn_s_barrier();
    __builtin_amdgcn_sched_barrier(0);

    #pragma unroll 1
    for (int t = 0; t < NT; ++t) {
        const unsigned short* Ab = &As[(t & 1) * ASLOT];
        const unsigned short* Bc = &Bs[(t & 1) * BSLOT];
        const int ns = (t + 1) & 1;
        short8 af[4], bf[3];

        // ---- P0: m0-3 x n0-2, kh0; stage A of t+1 ----
        #pragma unroll
        for (int i = 0; i < 4; ++i) af[i] = *(const short8*)&Ab[aoff[0][i]];
        #pragma unroll
        for (int n = 0; n < 3; ++n) bf[n] = *(const short8*)&Bc[boff[0][n]];
        if (t < NT - 1) stageA(ns);
        __builtin_amdgcn_sched_barrier(0);
        __builtin_amdgcn_s_barrier();
        asm volatile("s_waitcnt lgkmcnt(0)" ::: "memory");
        __builtin_amdgcn_s_setprio(1);
        #pragma unroll
        for (int i = 0; i < 4; ++i)
            #pragma unroll
            for (int n = 0; n < 3; ++n)
                acc[i][n] = __builtin_amdgcn_mfma_f32_16x16x32_bf16(af[i], bf[n], acc[i][n], 0, 0, 0);
        __builtin_amdgcn_s_setprio(0);
        __builtin_amdgcn_sched_barrier(0);
        __builtin_amdgcn_s_barrier();
        __builtin_amdgcn_sched_barrier(0);

        // ---- P1: m4-7 x n0-2, kh0 (B reg-cached); stage B of t+1 ----
        #pragma unroll
        for (int i = 0; i < 4; ++i) af[i] = *(const short8*)&Ab[aoff[0][4 + i]];
        if (t < NT - 1) stageB(ns);
        __builtin_amdgcn_sched_barrier(0);
        __builtin_amdgcn_s_barrier();
        asm volatile("s_waitcnt lgkmcnt(0)" ::: "memory");
        __builtin_amdgcn_s_setprio(1);
        #pragma unroll
        for (int i = 0; i < 4; ++i)
            #pragma unroll
            for (int n = 0; n < 3; ++n)
                acc[4 + i][n] = __builtin_amdgcn_mfma_f32_16x16x32_bf16(af[i], bf[n], acc[4 + i][n], 0, 0, 0);
        __builtin_amdgcn_s_setprio(0);
        __builtin_amdgcn_sched_barrier(0);
        __builtin_amdgcn_s_barrier();
        __builtin_amdgcn_sched_barrier(0);

        // ---- P2: m0-3 x n0-2, kh1 ----
        #pragma unroll
        for (int i = 0; i < 4; ++i) af[i] = *(const short8*)&Ab[aoff[1][i]];
        #pragma unroll
        for (int n = 0; n < 3; ++n) bf[n] = *(const short8*)&Bc[boff[1][n]];
        __builtin_amdgcn_sched_barrier(0);
        __builtin_amdgcn_s_barrier();
        asm volatile("s_waitcnt lgkmcnt(0)" ::: "memory");
        __builtin_amdgcn_s_setprio(1);
        #pragma unroll
        for (int i = 0; i < 4; ++i)
            #pragma unroll
            for (int n = 0; n < 3; ++n)
                acc[i][n] = __builtin_amdgcn_mfma_f32_16x16x32_bf16(af[i], bf[n], acc[i][n], 0, 0, 0);
        __builtin_amdgcn_s_setprio(0);
        __builtin_amdgcn_sched_barrier(0);
        __builtin_amdgcn_s_barrier();
        __builtin_amdgcn_sched_barrier(0);

        // ---- P3: m4-7 x n0-2, kh1; drain staging before releasing t+1 ----
        #pragma unroll
        for (int i = 0; i < 4; ++i) af[i] = *(const short8*)&Ab[aoff[1][4 + i]];
        __builtin_amdgcn_sched_barrier(0);
        __builtin_amdgcn_s_barrier();
        asm volatile("s_waitcnt lgkmcnt(0)" ::: "memory");
        __builtin_amdgcn_s_setprio(1);
        #pragma unroll
        for (int i = 0; i < 4; ++i)
            #pragma unroll
            for (int n = 0; n < 3; ++n)
                acc[4 + i][n] = __builtin_amdgcn_mfma_f32_16x16x32_bf16(af[i], bf[n], acc[4 + i][n], 0, 0, 0);
        __builtin_amdgcn_s_setprio(0);
        if (t < NT - 1) { asm volatile("s_waitcnt vmcnt(0)" ::: "memory"); }
        __builtin_amdgcn_sched_barrier(0);
        __builtin_amdgcn_s_barrier();
        __builtin_amdgcn_sched_barrier(0);
    }

    // ---- epilogue: z resolved PER-NI (192-wide tile straddles Q|K|V) ----
    #pragma unroll
    for (int n = 0; n < 3; ++n) {
        int n_g = nbase + wc * 48 + n * 16 + col;   // global stacked-n
        int z   = n_g >> 10;                        // 0:Q 1:K 2:V
        int nl  = n_g & 1023;
        int h = nl >> 6, dh0 = nl & 63;
        if (z < 2) {
            unsigned short* o = z ? outK : outQ;
            int p = dh0 >> 1;
            bool even = !(dh0 & 1);
            #pragma unroll
            for (int f = 0; f < 8; ++f)
                #pragma unroll
                for (int reg = 0; reg < 4; ++reg) {
                    int m_g = mbase + wr * 128 + f * 16 + quad * 4 + reg;
                    int b = m_g >> 11, s = m_g & 2047;
                    float v = acc[f][n][reg];
                    float part = __shfl_xor(v, 1, 64);
                    float c = cosT[s * HALF + p], sn = sinT[s * HALF + p];
                    float r = even ? (v * c - part * sn) : (v * c + part * sn);
                    o[((size_t)(b * H + h) * S + s) * Dh + dh0] = f2bf(r);
                }
        } else {
            #pragma unroll
            for (int f = 0; f < 8; ++f) {
                int m0 = mbase + wr * 128 + f * 16 + quad * 4;
                int b = m0 >> 11, s = m0 & 2047;
                ushort4 pk;
                pk.x = f2bf(acc[f][n][0]);
                pk.y = f2bf(acc[f][n][1]);
                pk.z = f2bf(acc[f][n][2]);
                pk.w = f2bf(acc[f][n][3]);
                *(ushort4*)&outV[((size_t)(b * H + h) * Dh + dh0) * S + s] = pk;
            }
        }
    }
}

// ---------------------------------------------------------------------------
// Out-projection bf16 MFMA GEMM v2b (unchanged): 64x64, BK=64, rot=r.
// ---------------------------------------------------------------------------
__global__ __launch_bounds__(256) void gemm_out_kernel(
    const unsigned short* __restrict__ A,
    const unsigned short* __restrict__ BT,
    float* __restrict__ outO, const float* __restrict__ bias)
{
    constexpr int BK   = 64;
    constexpr int ABUF = 64 * BK;     // 8 KB
    constexpr int BBUF = 64 * BK;     // 8 KB
    __shared__ __align__(16) unsigned short As[2 * ABUF];
    __shared__ __align__(16) unsigned short Bs[2 * BBUF];

    const int tid  = threadIdx.x;
    const int wave = tid >> 6;
    const int lane = tid & 63;
    const int col  = lane & 15;
    const int quad = lane >> 4;
    const int wy   = wave >> 1;
    const int wx   = wave & 1;

    const int mbase = blockIdx.y * 64;
    const int nbase = blockIdx.x * 64;

    const int srow8 = lane >> 3;      // 8 rows per gl_lds16 (row = 128B)
    const int sch8  = lane & 7;

    const unsigned short *pA[2], *pB[2];
    unsigned short *dA[2], *dB[2];
    #pragma unroll
    for (int w = 0; w < 2; ++w) {
        int base = wave * 16 + w * 8;
        int tr = base + srow8;
        pA[w] = A  + (size_t)(mbase + tr) * K + ((sch8 + tr) & 7) * 8;   // rot=r
        pB[w] = BT + (size_t)(nbase + tr) * K + ((sch8 + tr) & 7) * 8;   // rot=r
        dA[w] = &As[base * BK];
        dB[w] = &Bs[base * BK];
    }

    int aoff[2][2], boff[2][2];
    #pragma unroll
    for (int ks = 0; ks < 2; ++ks) {
        #pragma unroll
        for (int mi = 0; mi < 2; ++mi) {
            int r = wy * 32 + mi * 16 + col;
            aoff[ks][mi] = r * BK + (((ks * 4 + quad) - r) & 7) * 8;     // rot=r
        }
        #pragma unroll
        for (int ni = 0; ni < 2; ++ni) {
            int r = wx * 32 + ni * 16 + col;
            boff[ks][ni] = r * BK + (((ks * 4 + quad) - r) & 7) * 8;     // rot=r
        }
    }

    f32x4 acc[2][2];
    #pragma unroll
    for (int mi = 0; mi < 2; ++mi)
        #pragma unroll
        for (int ni = 0; ni < 2; ++ni) acc[mi][ni] = (f32x4)0.f;

    auto stage = [&](int buf) {
        #pragma unroll
        for (int w = 0; w < 2; ++w) { gl_lds16(pA[w], dA[w] + buf * ABUF); pA[w] += BK; }
        #pragma unroll
        for (int w = 0; w < 2; ++w) { gl_lds16(pB[w], dB[w] + buf * BBUF); pB[w] += BK; }
    };
    auto compute = [&](int buf) {
        const unsigned short* Ac = &As[buf * ABUF];
        const unsigned short* Bc = &Bs[buf * BBUF];
        #pragma unroll
        for (int ks = 0; ks < 2; ++ks) {
            short8 af[2], bfr[2];
            #pragma unroll
            for (int mi = 0; mi < 2; ++mi) af[mi] = *(const short8*)&Ac[aoff[ks][mi]];
            #pragma unroll
            for (int ni = 0; ni < 2; ++ni) bfr[ni] = *(const short8*)&Bc[boff[ks][ni]];
            #pragma unroll
            for (int mi = 0; mi < 2; ++mi)
                #pragma unroll
                for (int ni = 0; ni < 2; ++ni)
                    acc[mi][ni] = __builtin_amdgcn_mfma_f32_16x16x32_bf16(af[mi], bfr[ni], acc[mi][ni], 0, 0, 0);
        }
    };

    stage(0);
    #pragma unroll 1
    for (int kk = 0; kk < 16; kk += 2) {
        __syncthreads();
        if (kk + 1 < 16) stage(1);
        compute(0);
        __syncthreads();
        if (kk + 2 < 16) stage(0);
        compute(1);
    }

    #pragma unroll
    for (int ni = 0; ni < 2; ++ni) {
        int n_g = nbase + wx * 32 + ni * 16 + col;
        float bv = bias[n_g];
        #pragma unroll
        for (int mi = 0; mi < 2; ++mi)
            #pragma unroll
            for (int reg = 0; reg < 4; ++reg) {
                int m_g = mbase + wy * 32 + mi * 16 + quad * 4 + reg;
                outO[(size_t)m_g * N + n_g] = acc[mi][ni][reg] + bv;
            }
    }
}

// ---------------------------------------------------------------------------
// MFMA flash attention v13: 2x ILP per wave. attn is dependency-chain
// bound (r13: VALU 43%, Mfma 14%, FETCH 12MB, nothing saturated), so each
// wave now carries TWO independent 16-row q-groups (32 q-rows/wave) over
// the same K/V tiles -- the compiler interleaves the two QK->exp->Ps->PV
// chains, hiding each chain's latency under the other's work. 4 waves per
// block (256 thr), QBLK=128, grid (16,32), balanced pair/parity schedule
// and XCD-locality swizzle unchanged. LDS 48KB -> 3 blocks/CU.
// Boundary tile where g0 is fully masked but g1 isn't: handled by e=0.
// ---------------------------------------------------------------------------
__global__ __launch_bounds__(256, 3) void attn_mfma_kernel(
    const unsigned short* __restrict__ q, const unsigned short* __restrict__ k,
    const unsigned short* __restrict__ vt,
    float* __restrict__ Opart, float* __restrict__ lpart)
{
    constexpr int TSZ = 64 * 64;
    __shared__ __align__(16) unsigned short Ks[2 * TSZ];    // 16 KB
    __shared__ __align__(16) unsigned short Vs[2 * TSZ];    // 16 KB
    __shared__ __align__(16) unsigned short Ps[8][16 * 64]; // 16 KB, XOR-swizzled

    const int tid  = threadIdx.x;
    const int wave = tid >> 6;        // 0..3
    const int lane = tid & 63;
    const int col  = lane & 15;
    const int quad = lane >> 4;
    const int r8   = lane >> 3, cp = lane & 7;

    // XCD-locality swizzle: all 16 blocks of a bh share lin%8.
    const int lin   = (int)blockIdx.y * 16 + (int)blockIdx.x;
    const int bh    = (lin & 7) + 8 * ((lin >> 3) & 3);
    const int pairh = lin >> 5;       // 0..15
    const int pair  = pairh >> 1;     // 0..7
    const int hpar  = pairh & 1;      // key-tile parity this block owns

    const unsigned short* qb = q  + (size_t)bh * S * Dh;
    const unsigned short* kb = k  + (size_t)bh * S * Dh;
    const unsigned short* vb = vt + (size_t)bh * Dh * S;

    // staging: 4 waves x 16 rows (2 gl_lds16 each) cover the 64-row tile
    unsigned short* dk0 = &Ks[(wave * 16) * 64];
    unsigned short* dk1 = &Ks[(wave * 16 + 8) * 64];
    unsigned short* dv0 = &Vs[(wave * 16) * 64];
    unsigned short* dv1 = &Vs[(wave * 16 + 8) * 64];

    int foff[2][4];                   // K/V fragment reads, rot = local row
    #pragma unroll
    for (int ks = 0; ks < 2; ++ks)
        #pragma unroll
        for (int nt = 0; nt < 4; ++nt) {
            int r = nt * 16 + col;
            foff[ks][nt] = r * 64 + (((ks * 4 + quad) - r) & 7) * 8;
        }
    // Ps layout [row=16][key=64] shorts, 16B-chunk XOR swizzle: chunk ^= row&7
    int poffW[4][4];
    #pragma unroll
    for (int nt = 0; nt < 4; ++nt)
        #pragma unroll
        for (int reg = 0; reg < 4; ++reg) {
            int row = quad * 4 + reg;
            poffW[nt][reg] = row * 64 + (((nt * 2 + (col >> 3)) ^ (row & 7)) << 3) + (col & 7);
        }
    int poffR[2];
    #pragma unroll
    for (int ks = 0; ks < 2; ++ks)
        poffR[ks] = col * 64 + (((ks * 4 + quad) ^ (col & 7)) << 3);

    for (int phase = 0; phase < 2; ++phase) {
        const int qt  = phase ? (15 - pair) : pair;     // 128-row q-tile
        const int NV  = qt + 1;                         // visits this phase
        int wr0g[2];
        wr0g[0] = qt * 128 + wave * 32;                 // group 0 first q-row
        wr0g[1] = wr0g[0] + 16;                         // group 1 first q-row

        const unsigned short *pk0, *pk1, *pv0, *pv1;
        {
            int ra = wave * 16 + r8, rb = ra + 8;
            pk0 = kb + (size_t)(hpar * 64 + ra) * Dh + ((cp + ra) & 7) * 8;
            pk1 = kb + (size_t)(hpar * 64 + rb) * Dh + ((cp + rb) & 7) * 8;
            pv0 = vb + (size_t)ra * S + hpar * 64 + ((cp + ra) & 7) * 8;
            pv1 = vb + (size_t)rb * S + hpar * 64 + ((cp + rb) & 7) * 8;
        }
        auto stageKV = [&](int buf) {      // stage current tile, advance 2 tiles
            gl_lds16(pk0, dk0 + buf * TSZ); gl_lds16(pk1, dk1 + buf * TSZ);
            gl_lds16(pv0, dv0 + buf * TSZ); gl_lds16(pv1, dv1 + buf * TSZ);
            pk0 += 128 * Dh; pk1 += 128 * Dh;
            pv0 += 128;      pv1 += 128;
        };

        __syncthreads();                   // protect buffers from prev phase
        stageKV(0);

        short8 qfrag[2][2];
        #pragma unroll
        for (int g = 0; g < 2; ++g)
            #pragma unroll
            for (int ks = 0; ks < 2; ++ks)
                qfrag[g][ks] = *(const short8*)(qb + (size_t)(wr0g[g] + col) * Dh + ks * 32 + quad * 8);

        f32x4 O[2][4];
        float lacc[2][4];
        #pragma unroll
        for (int g = 0; g < 2; ++g) {
            #pragma unroll
            for (int nt = 0; nt < 4; ++nt) O[g][nt] = (f32x4)0.f;
            #pragma unroll
            for (int r = 0; r < 4; ++r) lacc[g][r] = 0.f;
        }

        auto subtile = [&](const unsigned short* Kc, const unsigned short* Vc, int t) {
            // --- QK^T, both groups (16 MFMA, independent chains) ---
            f32x4 sacc[2][4];
            #pragma unroll
            for (int g = 0; g < 2; ++g)
                #pragma unroll
                for (int nt = 0; nt < 4; ++nt) sacc[g][nt] = (f32x4)0.f;
            #pragma unroll
            for (int ks = 0; ks < 2; ++ks)
                #pragma unroll
                for (int nt = 0; nt < 4; ++nt) {
                    short8 kf = *(const short8*)&Kc[foff[ks][nt]];
                    #pragma unroll
                    for (int g = 0; g < 2; ++g)
                        sacc[g][nt] = __builtin_amdgcn_mfma_f32_16x16x32_bf16(qfrag[g][ks], kf, sacc[g][nt], 0, 0, 0);
                }
            // --- softmax numerator + row-sum + Ps writes, both groups ---
            float pb[2][4][4];
            #pragma unroll
            for (int g = 0; g < 2; ++g) {
                const bool edge = (t * 64 + 63 > wr0g[g]);
                #pragma unroll
                for (int nt = 0; nt < 4; ++nt) {
                    int key_g = t * 64 + nt * 16 + col;
                    #pragma unroll
                    for (int reg = 0; reg < 4; ++reg) {
                        // exp(s/8 - 8) = exp2(s * 0.125*log2e - 8*log2e)
                        float e = __builtin_amdgcn_exp2f(
                            fmaf(sacc[g][nt][reg], 0.18033688011112042f, -11.541560327111707f));
                        if (edge && key_g > wr0g[g] + quad * 4 + reg) e = 0.f;
                        pb[g][nt][reg] = e;
                    }
                }
                #pragma unroll
                for (int reg = 0; reg < 4; ++reg)
                    lacc[g][reg] += (pb[g][0][reg] + pb[g][1][reg]) + (pb[g][2][reg] + pb[g][3][reg]);
                #pragma unroll
                for (int nt = 0; nt < 4; ++nt)
                    #pragma unroll
                    for (int reg = 0; reg < 4; ++reg)
                        Ps[wave * 2 + g][poffW[nt][reg]] = f2bf(pb[g][nt][reg]);
            }
            // --- PV, both groups (16 MFMA) ---
            #pragma unroll
            for (int ks = 0; ks < 2; ++ks) {
                short8 pf0 = *(const short8*)&Ps[wave * 2 + 0][poffR[ks]];
                short8 pf1 = *(const short8*)&Ps[wave * 2 + 1][poffR[ks]];
                #pragma unroll
                for (int nt = 0; nt < 4; ++nt) {
                    short8 vf = *(const short8*)&Vc[foff[ks][nt]];
                    O[0][nt] = __builtin_amdgcn_mfma_f32_16x16x32_bf16(pf0, vf, O[0][nt], 0, 0, 0);
                    O[1][nt] = __builtin_amdgcn_mfma_f32_16x16x32_bf16(pf1, vf, O[1][nt], 0, 0, 0);
                }
            }
        };

        for (int j = 0; j < NV; ++j) {
            __syncthreads();               // drains prefetch of visit j
            if (j + 1 < NV) stageKV((j + 1) & 1);
            const int t = hpar + 2 * j;    // global 64-key tile index
            if (t * 64 <= wr0g[1] + 15)    // skip only if BOTH groups masked
                subtile(&Ks[(j & 1) * TSZ], &Vs[(j & 1) * TSZ], t);
        }

        #pragma unroll
        for (int g = 0; g < 2; ++g)
            #pragma unroll
            for (int reg = 0; reg < 4; ++reg) {
                float s = lacc[g][reg];
                #pragma unroll
                for (int off = 1; off <= 8; off <<= 1)
                    s += __shfl_xor(s, off, 64);
                lacc[g][reg] = s;
            }

        // write unnormalized fp32 partials (both groups)
        const size_t pb_base = (size_t)(hpar * 32 + bh) * S;
        #pragma unroll
        for (int g = 0; g < 2; ++g)
            #pragma unroll
            for (int reg = 0; reg < 4; ++reg) {
                int rg = wr0g[g] + quad * 4 + reg;
                float* op = Opart + (pb_base + rg) * 64 + col;
                #pragma unroll
                for (int nt = 0; nt < 4; ++nt)
                    op[nt * 16] = O[g][nt][reg];
                if (col == 0)
                    lpart[pb_base + rg] = lacc[g][reg];
            }
    }
}

// ---------------------------------------------------------------------------
// Split-K combine: ctx[b][q][h*64+d] = bf16( (O0+O1) / (l0+l1) ).
// ---------------------------------------------------------------------------
__global__ __launch_bounds__(256) void combine_kernel(
    const float* __restrict__ Opart, const float* __restrict__ lpart,
    unsigned short* __restrict__ ctx)
{
    int gid = blockIdx.x * 256 + threadIdx.x;     // 32*2048*16
    int bh  = gid >> 15;
    int rem = gid & 32767;
    int qr  = rem >> 4;
    int dg  = (rem & 15) << 2;

    size_t i0 = ((size_t)bh * S + qr) * 64 + dg;
    size_t i1 = ((size_t)(32 + bh) * S + qr) * 64 + dg;
    float4 a = *(const float4*)(Opart + i0);
    float4 c = *(const float4*)(Opart + i1);
    float inv = 1.0f / (lpart[(size_t)bh * S + qr] + lpart[(size_t)(32 + bh) * S + qr]);

    int b = bh >> 4, hh = bh & 15;
    ushort4 pk;
    pk.x = f2bf((a.x + c.x) * inv);
    pk.y = f2bf((a.y + c.y) * inv);
    pk.z = f2bf((a.z + c.z) * inv);
    pk.w = f2bf((a.w + c.w) * inv);
    *(ushort4*)(ctx + ((size_t)b * S + qr) * 1024 + hh * 64 + dg) = pk;
}

// ---------------------------------------------------------------------------
extern "C" void kernel_launch(void* const* d_in, const int* in_sizes, int n_in,
                              void* d_out, int out_size, void* d_ws, size_t ws_size,
                              hipStream_t stream) {
    const float* x  = (const float*)d_in[0];
    const float* Wq = (const float*)d_in[1];
    const float* Wk = (const float*)d_in[2];
    const float* Wv = (const float*)d_in[3];
    const float* Wo = (const float*)d_in[4];
    const float* bo = (const float*)d_in[5];
    float* out = (float*)d_out;

    const size_t MK  = (size_t)M * K;        // 4M
    const size_t NK  = (size_t)N * K;        // 1M
    const size_t QKV = (size_t)Bb * H * S * Dh;

    unsigned short* xb   = (unsigned short*)d_ws;
    unsigned short* WqT  = xb  + MK;         // WqT/WkT/WvT contiguous = stacked [3072][1024]
    unsigned short* WkT  = WqT + NK;
    unsigned short* WvT  = WkT + NK;
    unsigned short* WoT  = WvT + NK;
    unsigned short* qbuf = WoT + NK;
    unsigned short* kbuf = qbuf + QKV;
    unsigned short* vtb  = kbuf + QKV;
    unsigned short* ctxb = vtb  + QKV;
    float* cosT  = (float*)(ctxb + QKV);
    float* sinT  = cosT + (size_t)S * HALF;
    float* Opart = sinT + (size_t)S * HALF;               // 2*32*2048*64 fp32
    float* lpart = Opart + (size_t)2 * 32 * S * 64;       // 2*32*2048 fp32

    // fused prep: rope tables + x->bf16 + 4x W transpose->bf16
    prep_kernel<<<5376, 256, 0, stream>>>(x, Wq, Wk, Wv, Wo,
                                          xb, WqT, WkT, WvT, WoT, cosT, sinT);

    // fused QKV projections as one stacked-N GEMM (+RoPE, +V transpose)
    gemm_qkv_kernel<<<dim3(16, 16), 512, 0, stream>>>(
        xb, WqT, qbuf, kbuf, vtb, cosT, sinT);

    // flash attention v13: 2 q-groups per wave (2x ILP), 4-wave blocks
    attn_mfma_kernel<<<dim3(16, Bb * H), 256, 0, stream>>>(qbuf, kbuf, vtb, Opart, lpart);

    // split-K combine -> bf16 ctx
    combine_kernel<<<4096, 256, 0, stream>>>(Opart, lpart, ctxb);

    // output projection: 64x64 tiles, BK=64, 1024 blocks = 4/CU
    gemm_out_kernel<<<dim3(16, 64), 256, 0, stream>>>(ctxb, WoT, out, bo);
}

// Round 15
// 184.248 us; speedup vs baseline: 1.0133x; 1.0133x over previous
//
#include <hip/hip_runtime.h>
#include <hip/hip_bf16.h>
#include <math.h>

// Problem constants
constexpr int Bb   = 2;
constexpr int S    = 2048;
constexpr int D    = 1024;
constexpr int H    = 16;
constexpr int Dh   = 64;
constexpr int HALF = 32;            // Dh/2
constexpr int M    = Bb * S;        // 4096 rows in the projection GEMMs
constexpr int K    = 1024;
constexpr int N    = 1024;

typedef __attribute__((ext_vector_type(8))) short short8;   // 8 bf16 (4 VGPRs)
typedef __attribute__((ext_vector_type(4))) float f32x4;    // MFMA C/D

// float -> bf16 bits, round-to-nearest-even
__device__ __forceinline__ unsigned short f2bf(float f) {
    unsigned int u = __float_as_uint(f);
    unsigned int r = (u + 0x7fffu + ((u >> 16) & 1u)) >> 16;
    return (unsigned short)r;
}
__device__ __forceinline__ float b2f(unsigned short u) {
    return __uint_as_float((unsigned int)u << 16);
}

// async global->LDS, 16B per lane; LDS dest = wave-uniform base + lane*16
__device__ __forceinline__ void gl_lds16(const unsigned short* g, unsigned short* lds_base) {
    __builtin_amdgcn_global_load_lds(
        (const __attribute__((address_space(1))) unsigned int*)g,
        (__attribute__((address_space(3))) unsigned int*)lds_base, 16, 0, 0);
}

// ---------------------------------------------------------------------------
// Fused prep: blocks [0,256) rope tables (double precision),
// [256,4352) x fp32->bf16, [4352,5376) W fp32 [k][n] -> bf16 W^T [n][k].
// ---------------------------------------------------------------------------
__global__ __launch_bounds__(256) void prep_kernel(
    const float* __restrict__ x,
    const float* W0, const float* W1, const float* W2, const float* W3,
    unsigned short* __restrict__ xb,
    unsigned short* T0, unsigned short* T1, unsigned short* T2, unsigned short* T3,
    float* __restrict__ cosT, float* __restrict__ sinT)
{
    __shared__ float tile[64][65];
    const int bid = blockIdx.x;
    const int tid = threadIdx.x;

    if (bid < 256) {
        int idx = bid * 256 + tid;            // S*HALF = 65536
        int s = idx >> 5;
        int i = idx & 31;
        double freq = exp(-(double)i * (log(10000.0) / 32.0));
        double ang  = (double)s * freq;
        cosT[idx] = (float)cos(ang);
        sinT[idx] = (float)sin(ang);
    } else if (bid < 256 + 4096) {
        size_t i = (size_t)(bid - 256) * 256 + tid;   // over M*K/4
        float4 v = *(const float4*)(x + i * 4);
        ushort4 pk;
        pk.x = f2bf(v.x); pk.y = f2bf(v.y); pk.z = f2bf(v.z); pk.w = f2bf(v.w);
        *(ushort4*)(xb + i * 4) = pk;
    } else {
        int wb = bid - 4352;
        int z  = wb >> 8;
        int rem = wb & 255;
        const float* W = (z == 0) ? W0 : (z == 1) ? W1 : (z == 2) ? W2 : W3;
        unsigned short* T = (z == 0) ? T0 : (z == 1) ? T1 : (z == 2) ? T2 : T3;
        const int bk = (rem >> 4) * 64;   // src row block (k)
        const int bn = (rem & 15) * 64;   // src col block (n)
        const int lr = tid >> 4;          // 0..15
        const int lc = (tid & 15) * 4;    // float4 col

        #pragma unroll
        for (int i = 0; i < 4; ++i) {
            int r = lr + i * 16;
            float4 v = *(const float4*)(W + (size_t)(bk + r) * N + bn + lc);
            tile[r][lc + 0] = v.x; tile[r][lc + 1] = v.y;
            tile[r][lc + 2] = v.z; tile[r][lc + 3] = v.w;
        }
        __syncthreads();
        #pragma unroll
        for (int i = 0; i < 4; ++i) {
            int nr = lr + i * 16;
            ushort4 pk;
            pk.x = f2bf(tile[lc + 0][nr]);
            pk.y = f2bf(tile[lc + 1][nr]);
            pk.z = f2bf(tile[lc + 2][nr]);
            pk.w = f2bf(tile[lc + 3][nr]);
            *(ushort4*)(T + (size_t)(bn + nr) * K + bk + lc) = pk;
        }
    }
}

// ---------------------------------------------------------------------------
// QKV bf16 MFMA GEMM v6b (unchanged): BM=256 x BN=192, BK=64, 4-phase
// counted pipeline, grid (16,16) = 256 blocks = 1/CU. rot=r swizzle
// (bank conflicts 2.88M -> 0 verified r13).
// ---------------------------------------------------------------------------
__global__ __launch_bounds__(512, 2) void gemm_qkv_kernel(
    const unsigned short* __restrict__ A,
    const unsigned short* __restrict__ BT,
    unsigned short* outQ, unsigned short* outK, unsigned short* outV,
    const float* __restrict__ cosT, const float* __restrict__ sinT)
{
    constexpr int NT    = 16;           // K / 64 k-tiles
    constexpr int ASLOT = 256 * 64;     // shorts per A slot (32 KB)
    constexpr int BSLOT = 192 * 64;     // shorts per B slot (24 KB)
    __shared__ __align__(16) unsigned short As[2 * ASLOT];   // 64 KB
    __shared__ __align__(16) unsigned short Bs[2 * BSLOT];   // 48 KB

    const int tid  = threadIdx.x;
    const int wid  = tid >> 6;
    const int lane = tid & 63;
    const int col  = lane & 15;
    const int quad = lane >> 4;
    const int wr   = wid >> 2;        // m-half owner (0..1), 128 rows
    const int wc   = wid & 3;         // n-quarter owner (0..3), 48 cols

    const int mbase = blockIdx.y * 256;
    const int nbase = blockIdx.x * 192;

    const int srow8 = lane >> 3;      // 0..7
    const int sch8  = lane & 7;       // 16B chunk
    const unsigned short *pA[4], *pB[3];
    unsigned short *dA[4], *dB[3];
    #pragma unroll
    for (int w = 0; w < 4; ++w) {
        int r = wid * 32 + w * 8 + srow8;
        pA[w] = A + (size_t)(mbase + r) * K + ((sch8 + r) & 7) * 8;   // rot=r
        dA[w] = &As[(wid * 32 + w * 8) * 64];
    }
    #pragma unroll
    for (int w = 0; w < 3; ++w) {
        int r = wid * 24 + w * 8 + srow8;
        pB[w] = BT + (size_t)(nbase + r) * K + ((sch8 + r) & 7) * 8;  // rot=r
        dB[w] = &Bs[(wid * 24 + w * 8) * 64];
    }

    int aoff[2][8], boff[2][3];
    #pragma unroll
    for (int kh = 0; kh < 2; ++kh) {
        #pragma unroll
        for (int f = 0; f < 8; ++f) {
            int r = wr * 128 + f * 16 + col;
            aoff[kh][f] = r * 64 + (((kh * 4 + quad) - r) & 7) * 8;   // rot=r
        }
        #pragma unroll
        for (int n = 0; n < 3; ++n) {
            int r = wc * 48 + n * 16 + col;
            boff[kh][n] = r * 64 + (((kh * 4 + quad) - r) & 7) * 8;   // rot=r
        }
    }

    f32x4 acc[8][3];
    #pragma unroll
    for (int f = 0; f < 8; ++f)
        #pragma unroll
        for (int n = 0; n < 3; ++n) acc[f][n] = (f32x4)0.f;

    auto stageA = [&](int slot) {       // 4 instrs
        #pragma unroll
        for (int w = 0; w < 4; ++w) { gl_lds16(pA[w], dA[w] + slot * ASLOT); pA[w] += 64; }
    };
    auto stageB = [&](int slot) {       // 3 instrs
        #pragma unroll
        for (int w = 0; w < 3; ++w) { gl_lds16(pB[w], dB[w] + slot * BSLOT); pB[w] += 64; }
    };

    stageA(0); stageB(0);
    asm volatile("s_waitcnt vmcnt(0)" ::: "memory");
    __builtin_amdgcn_s_barrier();
    __builtin_amdgcn_sched_barrier(0);

    #pragma unroll 1
    for (int t = 0; t < NT; ++t) {
        const unsigned short* Ab = &As[(t & 1) * ASLOT];
        const unsigned short* Bc = &Bs[(t & 1) * BSLOT];
        const int ns = (t + 1) & 1;
        short8 af[4], bf[3];

        // ---- P0: m0-3 x n0-2, kh0; stage A of t+1 ----
        #pragma unroll
        for (int i = 0; i < 4; ++i) af[i] = *(const short8*)&Ab[aoff[0][i]];
        #pragma unroll
        for (int n = 0; n < 3; ++n) bf[n] = *(const short8*)&Bc[boff[0][n]];
        if (t < NT - 1) stageA(ns);
        __builtin_amdgcn_sched_barrier(0);
        __builtin_amdgcn_s_barrier();
        asm volatile("s_waitcnt lgkmcnt(0)" ::: "memory");
        __builtin_amdgcn_s_setprio(1);
        #pragma unroll
        for (int i = 0; i < 4; ++i)
            #pragma unroll
            for (int n = 0; n < 3; ++n)
                acc[i][n] = __builtin_amdgcn_mfma_f32_16x16x32_bf16(af[i], bf[n], acc[i][n], 0, 0, 0);
        __builtin_amdgcn_s_setprio(0);
        __builtin_amdgcn_sched_barrier(0);
        __builtin_amdgcn_s_barrier();
        __builtin_amdgcn_sched_barrier(0);

        // ---- P1: m4-7 x n0-2, kh0 (B reg-cached); stage B of t+1 ----
        #pragma unroll
        for (int i = 0; i < 4; ++i) af[i] = *(const short8*)&Ab[aoff[0][4 + i]];
        if (t < NT - 1) stageB(ns);
        __builtin_amdgcn_sched_barrier(0);
        __builtin_amdgcn_s_barrier();
        asm volatile("s_waitcnt lgkmcnt(0)" ::: "memory");
        __builtin_amdgcn_s_setprio(1);
        #pragma unroll
        for (int i = 0; i < 4; ++i)
            #pragma unroll
            for (int n = 0; n < 3; ++n)
                acc[4 + i][n] = __builtin_amdgcn_mfma_f32_16x16x32_bf16(af[i], bf[n], acc[4 + i][n], 0, 0, 0);
        __builtin_amdgcn_s_setprio(0);
        __builtin_amdgcn_sched_barrier(0);
        __builtin_amdgcn_s_barrier();
        __builtin_amdgcn_sched_barrier(0);

        // ---- P2: m0-3 x n0-2, kh1 ----
        #pragma unroll
        for (int i = 0; i < 4; ++i) af[i] = *(const short8*)&Ab[aoff[1][i]];
        #pragma unroll
        for (int n = 0; n < 3; ++n) bf[n] = *(const short8*)&Bc[boff[1][n]];
        __builtin_amdgcn_sched_barrier(0);
        __builtin_amdgcn_s_barrier();
        asm volatile("s_waitcnt lgkmcnt(0)" ::: "memory");
        __builtin_amdgcn_s_setprio(1);
        #pragma unroll
        for (int i = 0; i < 4; ++i)
            #pragma unroll
            for (int n = 0; n < 3; ++n)
                acc[i][n] = __builtin_amdgcn_mfma_f32_16x16x32_bf16(af[i], bf[n], acc[i][n], 0, 0, 0);
        __builtin_amdgcn_s_setprio(0);
        __builtin_amdgcn_sched_barrier(0);
        __builtin_amdgcn_s_barrier();
        __builtin_amdgcn_sched_barrier(0);

        // ---- P3: m4-7 x n0-2, kh1; drain staging before releasing t+1 ----
        #pragma unroll
        for (int i = 0; i < 4; ++i) af[i] = *(const short8*)&Ab[aoff[1][4 + i]];
        __builtin_amdgcn_sched_barrier(0);
        __builtin_amdgcn_s_barrier();
        asm volatile("s_waitcnt lgkmcnt(0)" ::: "memory");
        __builtin_amdgcn_s_setprio(1);
        #pragma unroll
        for (int i = 0; i < 4; ++i)
            #pragma unroll
            for (int n = 0; n < 3; ++n)
                acc[4 + i][n] = __builtin_amdgcn_mfma_f32_16x16x32_bf16(af[i], bf[n], acc[4 + i][n], 0, 0, 0);
        __builtin_amdgcn_s_setprio(0);
        if (t < NT - 1) { asm volatile("s_waitcnt vmcnt(0)" ::: "memory"); }
        __builtin_amdgcn_sched_barrier(0);
        __builtin_amdgcn_s_barrier();
        __builtin_amdgcn_sched_barrier(0);
    }

    // ---- epilogue: z resolved PER-NI (192-wide tile straddles Q|K|V) ----
    #pragma unroll
    for (int n = 0; n < 3; ++n) {
        int n_g = nbase + wc * 48 + n * 16 + col;   // global stacked-n
        int z   = n_g >> 10;                        // 0:Q 1:K 2:V
        int nl  = n_g & 1023;
        int h = nl >> 6, dh0 = nl & 63;
        if (z < 2) {
            unsigned short* o = z ? outK : outQ;
            int p = dh0 >> 1;
            bool even = !(dh0 & 1);
            #pragma unroll
            for (int f = 0; f < 8; ++f)
                #pragma unroll
                for (int reg = 0; reg < 4; ++reg) {
                    int m_g = mbase + wr * 128 + f * 16 + quad * 4 + reg;
                    int b = m_g >> 11, s = m_g & 2047;
                    float v = acc[f][n][reg];
                    float part = __shfl_xor(v, 1, 64);
                    float c = cosT[s * HALF + p], sn = sinT[s * HALF + p];
                    float r = even ? (v * c - part * sn) : (v * c + part * sn);
                    o[((size_t)(b * H + h) * S + s) * Dh + dh0] = f2bf(r);
                }
        } else {
            #pragma unroll
            for (int f = 0; f < 8; ++f) {
                int m0 = mbase + wr * 128 + f * 16 + quad * 4;
                int b = m0 >> 11, s = m0 & 2047;
                ushort4 pk;
                pk.x = f2bf(acc[f][n][0]);
                pk.y = f2bf(acc[f][n][1]);
                pk.z = f2bf(acc[f][n][2]);
                pk.w = f2bf(acc[f][n][3]);
                *(ushort4*)&outV[((size_t)(b * H + h) * Dh + dh0) * S + s] = pk;
            }
        }
    }
}

// ---------------------------------------------------------------------------
// Out-projection bf16 MFMA GEMM v2b (unchanged): 64x64, BK=64, rot=r.
// ---------------------------------------------------------------------------
__global__ __launch_bounds__(256) void gemm_out_kernel(
    const unsigned short* __restrict__ A,
    const unsigned short* __restrict__ BT,
    float* __restrict__ outO, const float* __restrict__ bias)
{
    constexpr int BK   = 64;
    constexpr int ABUF = 64 * BK;     // 8 KB
    constexpr int BBUF = 64 * BK;     // 8 KB
    __shared__ __align__(16) unsigned short As[2 * ABUF];
    __shared__ __align__(16) unsigned short Bs[2 * BBUF];

    const int tid  = threadIdx.x;
    const int wave = tid >> 6;
    const int lane = tid & 63;
    const int col  = lane & 15;
    const int quad = lane >> 4;
    const int wy   = wave >> 1;
    const int wx   = wave & 1;

    const int mbase = blockIdx.y * 64;
    const int nbase = blockIdx.x * 64;

    const int srow8 = lane >> 3;      // 8 rows per gl_lds16 (row = 128B)
    const int sch8  = lane & 7;

    const unsigned short *pA[2], *pB[2];
    unsigned short *dA[2], *dB[2];
    #pragma unroll
    for (int w = 0; w < 2; ++w) {
        int base = wave * 16 + w * 8;
        int tr = base + srow8;
        pA[w] = A  + (size_t)(mbase + tr) * K + ((sch8 + tr) & 7) * 8;   // rot=r
        pB[w] = BT + (size_t)(nbase + tr) * K + ((sch8 + tr) & 7) * 8;   // rot=r
        dA[w] = &As[base * BK];
        dB[w] = &Bs[base * BK];
    }

    int aoff[2][2], boff[2][2];
    #pragma unroll
    for (int ks = 0; ks < 2; ++ks) {
        #pragma unroll
        for (int mi = 0; mi < 2; ++mi) {
            int r = wy * 32 + mi * 16 + col;
            aoff[ks][mi] = r * BK + (((ks * 4 + quad) - r) & 7) * 8;     // rot=r
        }
        #pragma unroll
        for (int ni = 0; ni < 2; ++ni) {
            int r = wx * 32 + ni * 16 + col;
            boff[ks][ni] = r * BK + (((ks * 4 + quad) - r) & 7) * 8;     // rot=r
        }
    }

    f32x4 acc[2][2];
    #pragma unroll
    for (int mi = 0; mi < 2; ++mi)
        #pragma unroll
        for (int ni = 0; ni < 2; ++ni) acc[mi][ni] = (f32x4)0.f;

    auto stage = [&](int buf) {
        #pragma unroll
        for (int w = 0; w < 2; ++w) { gl_lds16(pA[w], dA[w] + buf * ABUF); pA[w] += BK; }
        #pragma unroll
        for (int w = 0; w < 2; ++w) { gl_lds16(pB[w], dB[w] + buf * BBUF); pB[w] += BK; }
    };
    auto compute = [&](int buf) {
        const unsigned short* Ac = &As[buf * ABUF];
        const unsigned short* Bc = &Bs[buf * BBUF];
        #pragma unroll
        for (int ks = 0; ks < 2; ++ks) {
            short8 af[2], bfr[2];
            #pragma unroll
            for (int mi = 0; mi < 2; ++mi) af[mi] = *(const short8*)&Ac[aoff[ks][mi]];
            #pragma unroll
            for (int ni = 0; ni < 2; ++ni) bfr[ni] = *(const short8*)&Bc[boff[ks][ni]];
            #pragma unroll
            for (int mi = 0; mi < 2; ++mi)
                #pragma unroll
                for (int ni = 0; ni < 2; ++ni)
                    acc[mi][ni] = __builtin_amdgcn_mfma_f32_16x16x32_bf16(af[mi], bfr[ni], acc[mi][ni], 0, 0, 0);
        }
    };

    stage(0);
    #pragma unroll 1
    for (int kk = 0; kk < 16; kk += 2) {
        __syncthreads();
        if (kk + 1 < 16) stage(1);
        compute(0);
        __syncthreads();
        if (kk + 2 < 16) stage(0);
        compute(1);
    }

    #pragma unroll
    for (int ni = 0; ni < 2; ++ni) {
        int n_g = nbase + wx * 32 + ni * 16 + col;
        float bv = bias[n_g];
        #pragma unroll
        for (int mi = 0; mi < 2; ++mi)
            #pragma unroll
            for (int reg = 0; reg < 4; ++reg) {
                int m_g = mbase + wy * 32 + mi * 16 + quad * 4 + reg;
                outO[(size_t)m_g * N + n_g] = acc[mi][ni][reg] + bv;
            }
    }
}

// ---------------------------------------------------------------------------
// MFMA flash attention v14: v11 8-wave structure (best measured 44.0us;
// v13's 2-group ILP was neutral -- shared per-wave lgkmcnt re-serializes
// the chains) with BF16 PARTIALS: Opart fp32->bf16 halves the split-K
// intermediate traffic (attn WRITE 34->17.8 MB, combine read 34->16.8 MB).
// lpart stays fp32 (exact denominators). QBLK=128, 2-way split-K parity,
// balanced pair schedule, XCD-locality swizzle.
// ---------------------------------------------------------------------------
__global__ __launch_bounds__(512, 4) void attn_mfma_kernel(
    const unsigned short* __restrict__ q, const unsigned short* __restrict__ k,
    const unsigned short* __restrict__ vt,
    unsigned short* __restrict__ Opart, float* __restrict__ lpart)
{
    constexpr int TSZ = 64 * 64;
    __shared__ __align__(16) unsigned short Ks[2 * TSZ];    // 16 KB
    __shared__ __align__(16) unsigned short Vs[2 * TSZ];    // 16 KB
    __shared__ __align__(16) unsigned short Ps[8][16 * 64]; // 16 KB, XOR-swizzled

    const int tid  = threadIdx.x;
    const int wave = tid >> 6;        // 0..7
    const int lane = tid & 63;
    const int col  = lane & 15;
    const int quad = lane >> 4;
    const int r8   = lane >> 3, cp = lane & 7;

    // XCD-locality swizzle: all 16 blocks of a bh share lin%8.
    const int lin   = (int)blockIdx.y * 16 + (int)blockIdx.x;
    const int bh    = (lin & 7) + 8 * ((lin >> 3) & 3);
    const int pairh = lin >> 5;       // 0..15
    const int pair  = pairh >> 1;     // 0..7
    const int hpar  = pairh & 1;      // key-tile parity this block owns

    const unsigned short* qb = q  + (size_t)bh * S * Dh;
    const unsigned short* kb = k  + (size_t)bh * S * Dh;
    const unsigned short* vb = vt + (size_t)bh * Dh * S;

    unsigned short* dk = &Ks[(wave * 8) * 64];
    unsigned short* dv = &Vs[(wave * 8) * 64];

    int foff[2][4];                   // K/V fragment reads, rot = local row
    #pragma unroll
    for (int ks = 0; ks < 2; ++ks)
        #pragma unroll
        for (int nt = 0; nt < 4; ++nt) {
            int r = nt * 16 + col;
            foff[ks][nt] = r * 64 + (((ks * 4 + quad) - r) & 7) * 8;
        }
    // Ps layout [row=16][key=64] shorts, 16B-chunk XOR swizzle: chunk ^= row&7
    int poffW[4][4];
    #pragma unroll
    for (int nt = 0; nt < 4; ++nt)
        #pragma unroll
        for (int reg = 0; reg < 4; ++reg) {
            int row = quad * 4 + reg;
            poffW[nt][reg] = row * 64 + (((nt * 2 + (col >> 3)) ^ (row & 7)) << 3) + (col & 7);
        }
    int poffR[2];
    #pragma unroll
    for (int ks = 0; ks < 2; ++ks)
        poffR[ks] = col * 64 + (((ks * 4 + quad) ^ (col & 7)) << 3);

    for (int phase = 0; phase < 2; ++phase) {
        const int qt  = phase ? (15 - pair) : pair;     // 128-row q-tile
        const int wr0 = qt * 128 + wave * 16;           // wave's first q-row
        const int NV  = qt + 1;                         // visits this phase

        const unsigned short *pk, *pv;
        {
            int r = wave * 8 + r8;
            pk = kb + (size_t)(hpar * 64 + r) * Dh + ((cp + r) & 7) * 8;
            pv = vb + (size_t)r * S + hpar * 64 + ((cp + r) & 7) * 8;
        }
        auto stageKV = [&](int buf) {      // stage current tile, advance 2 tiles
            gl_lds16(pk, dk + buf * TSZ);
            gl_lds16(pv, dv + buf * TSZ);
            pk += 128 * Dh;
            pv += 128;
        };

        __syncthreads();                   // protect buffers from prev phase
        stageKV(0);

        short8 qfrag[2];
        #pragma unroll
        for (int ks = 0; ks < 2; ++ks)
            qfrag[ks] = *(const short8*)(qb + (size_t)(wr0 + col) * Dh + ks * 32 + quad * 8);

        f32x4 O[4];
        float lacc[4];
        #pragma unroll
        for (int nt = 0; nt < 4; ++nt) O[nt] = (f32x4)0.f;
        #pragma unroll
        for (int r = 0; r < 4; ++r) lacc[r] = 0.f;

        auto subtile = [&](const unsigned short* Kc, const unsigned short* Vc, int t) {
            f32x4 sacc[4];
            #pragma unroll
            for (int nt = 0; nt < 4; ++nt) sacc[nt] = (f32x4)0.f;
            #pragma unroll
            for (int ks = 0; ks < 2; ++ks)
                #pragma unroll
                for (int nt = 0; nt < 4; ++nt) {
                    short8 kf = *(const short8*)&Kc[foff[ks][nt]];
                    sacc[nt] = __builtin_amdgcn_mfma_f32_16x16x32_bf16(qfrag[ks], kf, sacc[nt], 0, 0, 0);
                }
            const bool edge = (t * 64 + 63 > wr0);   // tile may exceed q-rows
            float pb[4][4];
            #pragma unroll
            for (int nt = 0; nt < 4; ++nt) {
                int key_g = t * 64 + nt * 16 + col;
                #pragma unroll
                for (int reg = 0; reg < 4; ++reg) {
                    // exp(s/8 - 8) = exp2(s * 0.125*log2e - 8*log2e)
                    float e = __builtin_amdgcn_exp2f(
                        fmaf(sacc[nt][reg], 0.18033688011112042f, -11.541560327111707f));
                    if (edge && key_g > wr0 + quad * 4 + reg) e = 0.f;
                    pb[nt][reg] = e;
                }
            }
            #pragma unroll
            for (int reg = 0; reg < 4; ++reg)
                lacc[reg] += (pb[0][reg] + pb[1][reg]) + (pb[2][reg] + pb[3][reg]);
            #pragma unroll
            for (int nt = 0; nt < 4; ++nt)
                #pragma unroll
                for (int reg = 0; reg < 4; ++reg)
                    Ps[wave][poffW[nt][reg]] = f2bf(pb[nt][reg]);
            #pragma unroll
            for (int ks = 0; ks < 2; ++ks) {
                short8 pf = *(const short8*)&Ps[wave][poffR[ks]];
                #pragma unroll
                for (int nt = 0; nt < 4; ++nt) {
                    short8 vf = *(const short8*)&Vc[foff[ks][nt]];
                    O[nt] = __builtin_amdgcn_mfma_f32_16x16x32_bf16(pf, vf, O[nt], 0, 0, 0);
                }
            }
        };

        for (int j = 0; j < NV; ++j) {
            __syncthreads();               // drains prefetch of visit j
            if (j + 1 < NV) stageKV((j + 1) & 1);
            const int t = hpar + 2 * j;    // global 64-key tile index
            if (t * 64 <= wr0 + 15)        // skip fully-masked tiles
                subtile(&Ks[(j & 1) * TSZ], &Vs[(j & 1) * TSZ], t);
        }

        #pragma unroll
        for (int reg = 0; reg < 4; ++reg) {
            float s = lacc[reg];
            #pragma unroll
            for (int off = 1; off <= 8; off <<= 1)
                s += __shfl_xor(s, off, 64);
            lacc[reg] = s;
        }

        // write unnormalized bf16 partials (+ fp32 row sums)
        const size_t pb_base = (size_t)(hpar * 32 + bh) * S;
        #pragma unroll
        for (int reg = 0; reg < 4; ++reg) {
            int rg = wr0 + quad * 4 + reg;
            unsigned short* op = Opart + (pb_base + rg) * 64 + col;
            #pragma unroll
            for (int nt = 0; nt < 4; ++nt)
                op[nt * 16] = f2bf(O[nt][reg]);
            if (col == 0)
                lpart[pb_base + rg] = lacc[reg];
        }
    }
}

// ---------------------------------------------------------------------------
// Split-K combine (bf16 partials): ctx = bf16( (O0+O1) / (l0+l1) ).
// Reads 16.8 MB instead of 33.5 (fp32) -> ~7us total with launch.
// ---------------------------------------------------------------------------
__global__ __launch_bounds__(256) void combine_kernel(
    const unsigned short* __restrict__ Opart, const float* __restrict__ lpart,
    unsigned short* __restrict__ ctx)
{
    int gid = blockIdx.x * 256 + threadIdx.x;     // 32*2048*16
    int bh  = gid >> 15;
    int rem = gid & 32767;
    int qr  = rem >> 4;
    int dg  = (rem & 15) << 2;

    size_t r0 = (size_t)bh * S + qr;
    size_t r1 = (size_t)(32 + bh) * S + qr;
    ushort4 a = *(const ushort4*)(Opart + r0 * 64 + dg);
    ushort4 c = *(const ushort4*)(Opart + r1 * 64 + dg);
    float inv = 1.0f / (lpart[r0] + lpart[r1]);

    int b = bh >> 4, hh = bh & 15;
    ushort4 pk;
    pk.x = f2bf((b2f(a.x) + b2f(c.x)) * inv);
    pk.y = f2bf((b2f(a.y) + b2f(c.y)) * inv);
    pk.z = f2bf((b2f(a.z) + b2f(c.z)) * inv);
    pk.w = f2bf((b2f(a.w) + b2f(c.w)) * inv);
    *(ushort4*)(ctx + ((size_t)b * S + qr) * 1024 + hh * 64 + dg) = pk;
}

// ---------------------------------------------------------------------------
extern "C" void kernel_launch(void* const* d_in, const int* in_sizes, int n_in,
                              void* d_out, int out_size, void* d_ws, size_t ws_size,
                              hipStream_t stream) {
    const float* x  = (const float*)d_in[0];
    const float* Wq = (const float*)d_in[1];
    const float* Wk = (const float*)d_in[2];
    const float* Wv = (const float*)d_in[3];
    const float* Wo = (const float*)d_in[4];
    const float* bo = (const float*)d_in[5];
    float* out = (float*)d_out;

    const size_t MK  = (size_t)M * K;        // 4M
    const size_t NK  = (size_t)N * K;        // 1M
    const size_t QKV = (size_t)Bb * H * S * Dh;

    unsigned short* xb   = (unsigned short*)d_ws;
    unsigned short* WqT  = xb  + MK;         // WqT/WkT/WvT contiguous = stacked [3072][1024]
    unsigned short* WkT  = WqT + NK;
    unsigned short* WvT  = WkT + NK;
    unsigned short* WoT  = WvT + NK;
    unsigned short* qbuf = WoT + NK;
    unsigned short* kbuf = qbuf + QKV;
    unsigned short* vtb  = kbuf + QKV;
    unsigned short* ctxb = vtb  + QKV;
    float* cosT = (float*)(ctxb + QKV);
    float* sinT = cosT + (size_t)S * HALF;
    unsigned short* Opart = (unsigned short*)(sinT + (size_t)S * HALF); // 2*32*S*64 bf16
    float* lpart = (float*)(Opart + (size_t)2 * 32 * S * 64);           // 2*32*S fp32

    // fused prep: rope tables + x->bf16 + 4x W transpose->bf16
    prep_kernel<<<5376, 256, 0, stream>>>(x, Wq, Wk, Wv, Wo,
                                          xb, WqT, WkT, WvT, WoT, cosT, sinT);

    // fused QKV projections as one stacked-N GEMM (+RoPE, +V transpose)
    gemm_qkv_kernel<<<dim3(16, 16), 512, 0, stream>>>(
        xb, WqT, qbuf, kbuf, vtb, cosT, sinT);

    // flash attention v14: v11 structure, bf16 partials
    attn_mfma_kernel<<<dim3(16, Bb * H), 512, 0, stream>>>(qbuf, kbuf, vtb, Opart, lpart);

    // split-K combine (bf16 partials) -> bf16 ctx
    combine_kernel<<<4096, 256, 0, stream>>>(Opart, lpart, ctxb);

    // output projection: 64x64 tiles, BK=64, 1024 blocks = 4/CU
    gemm_out_kernel<<<dim3(16, 64), 256, 0, stream>>>(ctxb, WoT, out, bo);
}